// Round 1
// baseline (223.028 us; speedup 1.0000x reference)
//
#include <hip/hip_runtime.h>

#define N 8192
#define CAP 64          // max out-edges per box (expected max ~15)
#define THR 0.2f

// ---------------- rank: rank[i] = #{j: s_j > s_i or (s_j==s_i and j<i)} ----------------
__global__ __launch_bounds__(256) void rank_kernel(const float* __restrict__ scores,
                                                   unsigned* __restrict__ rank) {
    __shared__ float s[1024];
    const int jbase = blockIdx.y * 1024;
    for (int t = threadIdx.x; t < 1024; t += 256) s[t] = scores[jbase + t];
    __syncthreads();
    const int i = blockIdx.x * 256 + threadIdx.x;
    const float si = scores[i];
    unsigned c = 0;
    #pragma unroll 8
    for (int jj = 0; jj < 1024; ++jj) {
        float sj = s[jj];
        int j = jbase + jj;
        c += (sj > si) || (sj == si && j < i);
    }
    atomicAdd(&rank[i], c);
}

// ---------------- scatter into sorted order ----------------
__global__ __launch_bounds__(256) void scatter_kernel(const float* __restrict__ rois,
                                                      const unsigned* __restrict__ rank,
                                                      unsigned* __restrict__ order,
                                                      float4* __restrict__ sboxes) {
    const int i = blockIdx.x * 256 + threadIdx.x;
    const unsigned r = rank[i];
    order[r] = (unsigned)i;
    sboxes[r] = ((const float4*)rois)[i];
}

// ---------------- IoU (contraction-safe, matches numpy op order) ----------------
__device__ __forceinline__ bool iou_over(const float4 A, const float4 B) {
    float areaA = __fmul_rn(__fsub_rn(A.z, A.x), __fsub_rn(A.w, A.y));
    float areaB = __fmul_rn(__fsub_rn(B.z, B.x), __fsub_rn(B.w, B.y));
    float ix1 = fmaxf(A.x, B.x);
    float iy1 = fmaxf(A.y, B.y);
    float ix2 = fminf(A.z, B.z);
    float iy2 = fminf(A.w, B.w);
    float iw = fmaxf(__fsub_rn(ix2, ix1), 0.0f);
    float ih = fmaxf(__fsub_rn(iy2, iy1), 0.0f);
    float inter = __fmul_rn(iw, ih);
    float uni = __fsub_rn(__fadd_rn(areaA, areaB), inter);
    float iou = __fdiv_rn(inter, fmaxf(uni, 1e-9f));
    return iou > THR;
}

// ---------------- build sparse suppression structures over upper triangle ----------------
__global__ __launch_bounds__(256) void edge_kernel(const float4* __restrict__ sboxes,
                                                   unsigned long long* __restrict__ premask,
                                                   unsigned* __restrict__ cnt,
                                                   unsigned short* __restrict__ edges) {
    const int ti = blockIdx.x, tj = blockIdx.y;
    if (tj < ti) return;
    __shared__ float4 rb[64], cb[64];
    const int t = threadIdx.x;
    if (t < 64) rb[t] = sboxes[ti * 64 + t];
    else if (t < 128) cb[t - 64] = sboxes[tj * 64 + (t - 64)];
    __syncthreads();
    #pragma unroll
    for (int k = 0; k < 16; ++k) {
        int p = k * 256 + t;          // 0..4095
        int r = p >> 6, c = p & 63;
        int is = ti * 64 + r, js = tj * 64 + c;
        if (js <= is) continue;
        if (iou_over(rb[r], cb[c])) {
            if (ti == tj) {
                atomicOr(&premask[js], 1ull << r);
            } else {
                unsigned pos = atomicAdd(&cnt[is], 1u);
                if (pos < CAP) edges[is * CAP + pos] = (unsigned short)js;
            }
        }
    }
}

// ---------------- sequential greedy resolve: 1 wave, 128 chunks of 64 ----------------
__global__ __launch_bounds__(64) void resolve_kernel(const unsigned long long* __restrict__ premask,
                                                     const unsigned* __restrict__ cnt,
                                                     const unsigned short* __restrict__ edges,
                                                     unsigned long long* __restrict__ keptw) {
    __shared__ unsigned alive[256];       // 8192-bit alive bitmap
    const int lane = threadIdx.x;
    for (int w = lane; w < 256; w += 64) alive[w] = 0xFFFFFFFFu;
    __syncthreads();

    unsigned long long pm = premask[lane];
    unsigned n = cnt[lane];

    for (int c = 0; c < 128; ++c) {
        unsigned long long pm_next = 0ull;
        unsigned n_next = 0u;
        if (c < 127) {
            pm_next = premask[(c + 1) * 64 + lane];
            n_next  = cnt[(c + 1) * 64 + lane];
        }
        const int b = c * 64 + lane;
        const unsigned av = (alive[b >> 5] >> (b & 31)) & 1u;

        unsigned long long kept = __ballot(av && pm == 0ull);
        unsigned long long rem  = __ballot(av && pm != 0ull);
        while (rem) {
            int l = __builtin_ctzll(rem);
            rem &= rem - 1;
            unsigned lo = __shfl((unsigned)pm, l);
            unsigned hi = __shfl((unsigned)(pm >> 32), l);
            unsigned long long pml = ((unsigned long long)hi << 32) | lo;
            if (!(pml & kept)) kept |= 1ull << l;
        }

        if ((kept >> lane) & 1ull) {
            unsigned nn = n > CAP ? CAP : n;
            for (unsigned e = 0; e < nn; ++e) {
                unsigned d = edges[b * CAP + e];
                atomicAnd(&alive[d >> 5], ~(1u << (d & 31)));
            }
        }
        if (lane == 0) keptw[c] = kept;
        __syncthreads();
        pm = pm_next;
        n = n_next;
    }
}

// ---------------- scatter output back through permutation ----------------
__global__ __launch_bounds__(256) void out_kernel(const float* __restrict__ scores,
                                                  const unsigned* __restrict__ order,
                                                  const unsigned long long* __restrict__ keptw,
                                                  float* __restrict__ out) {
    const int s = blockIdx.x * 256 + threadIdx.x;
    const unsigned orig = order[s];
    const unsigned keep = (unsigned)((keptw[s >> 6] >> (s & 63)) & 1ull);
    out[orig] = keep ? scores[orig] : 0.0f;
}

extern "C" void kernel_launch(void* const* d_in, const int* in_sizes, int n_in,
                              void* d_out, int out_size, void* d_ws, size_t ws_size,
                              hipStream_t stream) {
    const float* rois   = (const float*)d_in[0];
    const float* scores = (const float*)d_in[1];
    float* out = (float*)d_out;

    char* ws = (char*)d_ws;
    unsigned*            rank    = (unsigned*)(ws);                       // 32 KB
    unsigned*            cnt     = (unsigned*)(ws + 32768);               // 32 KB
    unsigned long long*  premask = (unsigned long long*)(ws + 65536);     // 64 KB
    unsigned*            order   = (unsigned*)(ws + 131072);              // 32 KB
    float4*              sboxes  = (float4*)(ws + 163840);                // 128 KB
    unsigned long long*  keptw   = (unsigned long long*)(ws + 294912);    // 1 KB
    unsigned short*      edges   = (unsigned short*)(ws + 295936);        // 1 MB

    // zero rank, cnt, premask (first 128 KB)
    hipMemsetAsync(ws, 0, 131072, stream);

    rank_kernel<<<dim3(32, 8), 256, 0, stream>>>(scores, rank);
    scatter_kernel<<<32, 256, 0, stream>>>(rois, rank, order, sboxes);
    edge_kernel<<<dim3(128, 128), 256, 0, stream>>>(sboxes, premask, cnt, edges);
    resolve_kernel<<<1, 64, 0, stream>>>(premask, cnt, edges, keptw);
    out_kernel<<<32, 256, 0, stream>>>(scores, order, keptw, out);
}

// Round 2
// 167.205 us; speedup vs baseline: 1.3339x; 1.3339x over previous
//
#include <hip/hip_runtime.h>

#define N 8192
#define CAP 64          // max out-edges per box stored (expected max ~20)
#define THR 0.2f

// ---------------- rank: rank[i] = #{j: s_j > s_i or (s_j==s_i and j<i)} ----------------
__global__ __launch_bounds__(256) void rank_kernel(const float* __restrict__ scores,
                                                   unsigned* __restrict__ rank) {
    __shared__ float s[1024];
    const int jbase = blockIdx.y * 1024;
    for (int t = threadIdx.x; t < 1024; t += 256) s[t] = scores[jbase + t];
    __syncthreads();
    const int i = blockIdx.x * 256 + threadIdx.x;
    const float si = scores[i];
    unsigned c = 0;
    #pragma unroll 8
    for (int jj = 0; jj < 1024; ++jj) {
        float sj = s[jj];
        int j = jbase + jj;
        c += (sj > si) || (sj == si && j < i);
    }
    atomicAdd(&rank[i], c);
}

// ---------------- scatter into sorted order ----------------
__global__ __launch_bounds__(256) void scatter_kernel(const float* __restrict__ rois,
                                                      const unsigned* __restrict__ rank,
                                                      unsigned* __restrict__ order,
                                                      float4* __restrict__ sboxes) {
    const int i = blockIdx.x * 256 + threadIdx.x;
    const unsigned r = rank[i];
    order[r] = (unsigned)i;
    sboxes[r] = ((const float4*)rois)[i];
}

// ---------------- IoU (contraction-safe, matches numpy op order) ----------------
__device__ __forceinline__ bool iou_over(const float4 A, const float4 B) {
    float areaA = __fmul_rn(__fsub_rn(A.z, A.x), __fsub_rn(A.w, A.y));
    float areaB = __fmul_rn(__fsub_rn(B.z, B.x), __fsub_rn(B.w, B.y));
    float ix1 = fmaxf(A.x, B.x);
    float iy1 = fmaxf(A.y, B.y);
    float ix2 = fminf(A.z, B.z);
    float iy2 = fminf(A.w, B.w);
    float iw = fmaxf(__fsub_rn(ix2, ix1), 0.0f);
    float ih = fmaxf(__fsub_rn(iy2, iy1), 0.0f);
    float inter = __fmul_rn(iw, ih);
    float uni = __fsub_rn(__fadd_rn(areaA, areaB), inter);
    float iou = __fdiv_rn(inter, fmaxf(uni, 1e-9f));
    return iou > THR;
}

// ---------------- build sparse suppression structures over upper triangle ----------------
__global__ __launch_bounds__(256) void edge_kernel(const float4* __restrict__ sboxes,
                                                   unsigned long long* __restrict__ premask,
                                                   unsigned* __restrict__ cnt,
                                                   unsigned short* __restrict__ edges) {
    const int ti = blockIdx.x, tj = blockIdx.y;
    if (tj < ti) return;
    __shared__ float4 rb[64], cb[64];
    const int t = threadIdx.x;
    if (t < 64) rb[t] = sboxes[ti * 64 + t];
    else if (t < 128) cb[t - 64] = sboxes[tj * 64 + (t - 64)];
    __syncthreads();
    #pragma unroll
    for (int k = 0; k < 16; ++k) {
        int p = k * 256 + t;          // 0..4095
        int r = p >> 6, c = p & 63;
        int is = ti * 64 + r, js = tj * 64 + c;
        if (js <= is) continue;
        if (iou_over(rb[r], cb[c])) {
            if (ti == tj) {
                atomicOr(&premask[js], 1ull << r);
            } else {
                unsigned pos = atomicAdd(&cnt[is], 1u);
                if (pos < CAP) edges[is * CAP + pos] = (unsigned short)js;
            }
        }
    }
}

// ---------------- sequential greedy resolve: 1 wave, 128 chunks of 64 ----------------
// 8-deep register prefetch pipeline; no vmcnt drains in the loop.

#define PF(B, CH) do { \
    int ch_ = (CH); \
    if (ch_ < 128) { \
        int pb_ = ch_ * 64 + lane; \
        pm##B = premask[pb_]; \
        n##B  = cnt[pb_]; \
        e##B  = *(const uint4*)(edges + (size_t)pb_ * CAP); \
    } \
} while (0)

#define EDGE1(i, W, SH) \
    if ((i) < nn) { unsigned d_ = ((W) >> (SH)) & 0xFFFFu; atomicAnd(&alive[d_ >> 5], ~(1u << (d_ & 31))); }

#define STEP(B, C) do { \
    const int b_ = (C) * 64 + lane; \
    const unsigned av_ = (alive[b_ >> 5] >> (b_ & 31)) & 1u; \
    unsigned long long kept = __ballot(av_ && (pm##B == 0ull)); \
    unsigned long long rem  = __ballot(av_ && (pm##B != 0ull)); \
    while (rem) { \
        int l_ = __builtin_ctzll(rem); rem &= rem - 1; \
        unsigned lo_ = __shfl((unsigned)pm##B, l_); \
        unsigned hi_ = __shfl((unsigned)(pm##B >> 32), l_); \
        unsigned long long pml_ = ((unsigned long long)hi_ << 32) | lo_; \
        if (!(pml_ & kept)) kept |= 1ull << l_; \
    } \
    if ((kept >> lane) & 1ull) { \
        unsigned nn = n##B > CAP ? CAP : n##B; \
        EDGE1(0u, e##B.x, 0) EDGE1(1u, e##B.x, 16) \
        EDGE1(2u, e##B.y, 0) EDGE1(3u, e##B.y, 16) \
        EDGE1(4u, e##B.z, 0) EDGE1(5u, e##B.z, 16) \
        EDGE1(6u, e##B.w, 0) EDGE1(7u, e##B.w, 16) \
        for (unsigned e2_ = 8; e2_ < nn; ++e2_) { \
            unsigned d_ = edges[(size_t)b_ * CAP + e2_]; \
            atomicAnd(&alive[d_ >> 5], ~(1u << (d_ & 31))); \
        } \
    } \
    if (lane == 0) keptw[(C)] = kept; \
    PF(B, (C) + 8); \
    asm volatile("s_waitcnt lgkmcnt(0)" ::: "memory"); \
} while (0)

__global__ __launch_bounds__(64) void resolve_kernel(const unsigned long long* __restrict__ premask,
                                                     const unsigned* __restrict__ cnt,
                                                     const unsigned short* __restrict__ edges,
                                                     unsigned long long* __restrict__ keptw) {
    __shared__ unsigned alive[256];       // 8192-bit alive bitmap
    const int lane = threadIdx.x;
    #pragma unroll
    for (int w = 0; w < 4; ++w) alive[w * 64 + lane] = 0xFFFFFFFFu;
    asm volatile("s_waitcnt lgkmcnt(0)" ::: "memory");

    unsigned long long pm0, pm1, pm2, pm3, pm4, pm5, pm6, pm7;
    unsigned n0, n1, n2, n3, n4, n5, n6, n7;
    uint4 e0, e1, e2, e3, e4, e5, e6, e7;

    PF(0, 0); PF(1, 1); PF(2, 2); PF(3, 3);
    PF(4, 4); PF(5, 5); PF(6, 6); PF(7, 7);

    for (int cc = 0; cc < 128; cc += 8) {
        STEP(0, cc + 0); STEP(1, cc + 1); STEP(2, cc + 2); STEP(3, cc + 3);
        STEP(4, cc + 4); STEP(5, cc + 5); STEP(6, cc + 6); STEP(7, cc + 7);
    }
}

// ---------------- scatter output back through permutation ----------------
__global__ __launch_bounds__(256) void out_kernel(const float* __restrict__ scores,
                                                  const unsigned* __restrict__ order,
                                                  const unsigned long long* __restrict__ keptw,
                                                  float* __restrict__ out) {
    const int s = blockIdx.x * 256 + threadIdx.x;
    const unsigned orig = order[s];
    const unsigned keep = (unsigned)((keptw[s >> 6] >> (s & 63)) & 1ull);
    out[orig] = keep ? scores[orig] : 0.0f;
}

extern "C" void kernel_launch(void* const* d_in, const int* in_sizes, int n_in,
                              void* d_out, int out_size, void* d_ws, size_t ws_size,
                              hipStream_t stream) {
    const float* rois   = (const float*)d_in[0];
    const float* scores = (const float*)d_in[1];
    float* out = (float*)d_out;

    char* ws = (char*)d_ws;
    unsigned*            rank    = (unsigned*)(ws);                       // 32 KB
    unsigned*            cnt     = (unsigned*)(ws + 32768);               // 32 KB
    unsigned long long*  premask = (unsigned long long*)(ws + 65536);     // 64 KB
    unsigned*            order   = (unsigned*)(ws + 131072);              // 32 KB
    float4*              sboxes  = (float4*)(ws + 163840);                // 128 KB
    unsigned long long*  keptw   = (unsigned long long*)(ws + 294912);    // 1 KB
    unsigned short*      edges   = (unsigned short*)(ws + 295936);        // 1 MB

    // zero rank, cnt, premask (first 128 KB)
    hipMemsetAsync(ws, 0, 131072, stream);

    rank_kernel<<<dim3(32, 8), 256, 0, stream>>>(scores, rank);
    scatter_kernel<<<32, 256, 0, stream>>>(rois, rank, order, sboxes);
    edge_kernel<<<dim3(128, 128), 256, 0, stream>>>(sboxes, premask, cnt, edges);
    resolve_kernel<<<1, 64, 0, stream>>>(premask, cnt, edges, keptw);
    out_kernel<<<32, 256, 0, stream>>>(scores, order, keptw, out);
}